// Round 11
// baseline (5930.928 us; speedup 1.0000x reference)
//
#include <hip/hip_runtime.h>

#define IN 10
#define HID 128
#define OUT 4

// Dequantized f32 weights (static device globals; rewritten every launch).
__device__ float g_W1qf[HID * IN];
__device__ float g_W2qf[HID * HID];
__device__ float g_W3qf[OUT * HID];

// ---------- asm-protected f32 ops (immune to fast-math/reassoc/contract) ----------
__device__ __forceinline__ float f_fma(float a, float b, float c) {
    float d; asm("v_fma_f32 %0, %1, %2, %3" : "=v"(d) : "v"(a), "v"(b), "v"(c)); return d;
}
__device__ __forceinline__ float f_fma_s(float a, float w, float c) {   // 1 SGPR legal in VOP3
    float d; asm("v_fma_f32 %0, %1, %2, %3" : "=v"(d) : "v"(a), "s"(w), "v"(c)); return d;
}
__device__ __forceinline__ float f_mul(float a, float b) {
    float d; asm("v_mul_f32 %0, %1, %2" : "=v"(d) : "v"(a), "v"(b)); return d;
}
__device__ __forceinline__ float f_add(float a, float b) {
    float d; asm("v_add_f32 %0, %1, %2" : "=v"(d) : "v"(a), "v"(b)); return d;
}
__device__ __forceinline__ float f_sub(float a, float b) {
    float d; asm("v_sub_f32 %0, %1, %2" : "=v"(d) : "v"(a), "v"(b)); return d;
}
__device__ __forceinline__ float f_rndne(float a) {   // round half to even = np.round
    float d; asm("v_rndne_f32 %0, %1" : "=v"(d) : "v"(a)); return d;
}
__device__ __forceinline__ float f_rcp(float a) {
    float d; asm("v_rcp_f32 %0, %1" : "=v"(d) : "v"(a)); return d;
}

// Correctly-rounded IEEE f32 division (Markstein): rcp + 2 NR (exact asm FMA)
// + residual correction. d.y alone is the correctly-rounded reciprocal 1/s
// (== what XLA's reciprocal / vdivps(1,s) produces).
struct DivCR { float y, ns; };
__device__ __forceinline__ DivCR make_div(float s) {
    DivCR d;
    d.ns = f_sub(0.0f, s);                 // exact -s
    float y0 = f_rcp(s);
    float e0 = f_fma(d.ns, y0, 1.0f);
    float y1 = f_fma(e0, y0, y0);
    float e1 = f_fma(d.ns, y1, 1.0f);
    d.y = f_fma(e1, y1, y1);               // CR reciprocal
    return d;
}
__device__ __forceinline__ float div_cr(float h, DivCR d) {
    float q0 = f_mul(h, d.y);
    float r  = f_fma(d.ns, q0, h);         // exact residual
    return f_fma(r, d.y, q0);              // correctly-rounded quotient
}

// prep: f32 max-reduce -> s = max/7 (CR divide; constant-7 div is NOT rewritten
// by XLA's pow2-gated const rule) -> codes via W * (1/s) [XLA's div->recip-mul
// rewrite for scalar-broadcast divisors] -> Wq = clip(rndne(W*(1/s)),-7,7)*s.
__global__ void prep_kernel(const float* __restrict__ W1,
                            const float* __restrict__ W2,
                            const float* __restrict__ W3) {
    __shared__ float red[256];
    __shared__ float sS;
    const int t = threadIdx.x;
    const int which = blockIdx.x;

    const float* W; float* Wo; int n;
    if (which == 0)      { W = W1; Wo = g_W1qf; n = HID * IN; }
    else if (which == 1) { W = W2; Wo = g_W2qf; n = HID * HID; }
    else                 { W = W3; Wo = g_W3qf; n = OUT * HID; }

    float mx = 0.f;
    for (int i = t; i < n; i += 256) mx = fmaxf(mx, fabsf(W[i]));
    red[t] = mx;
    __syncthreads();
    for (int s = 128; s > 0; s >>= 1) {
        if (t < s) red[t] = fmaxf(red[t], red[t + s]);
        __syncthreads();
    }
    if (t == 0) {
        DivCR d7 = make_div(7.0f);
        sS = div_cr(red[0], d7);           // IEEE f32 max/7
    }
    __syncthreads();
    const float s = sS;
    const float rs = make_div(s).y;        // CR 1/s

    for (int i = t; i < n; i += 256) {
        float r = f_rndne(f_mul(W[i], rs));   // W * (1/s), single rounding
        r = fminf(7.f, fmaxf(-7.f, r));
        Wo[i] = f_mul(r, s);
    }
}

__global__ __launch_bounds__(256) void mlp_kernel(
    const float* __restrict__ m,
    const float* __restrict__ b1,
    const float* __restrict__ b2,
    const float* __restrict__ b3,
    const float* __restrict__ s_act1,
    const float* __restrict__ s_act2,
    float* __restrict__ out, int nrows)
{
    // Per-thread quant-code scratch (dynamic j index -> LDS keeps regs static).
    __shared__ unsigned char codes8[256 * 132];
    unsigned int* codes = (unsigned int*)codes8;

    const int t = threadIdx.x;
    const int row = blockIdx.x * 256 + t;
    if (row >= nrows) return;

    const float s1 = s_act1[0];
    const float s2 = s_act2[0];
    const float r1 = make_div(s1).y;       // CR 1/s1 (XLA: reciprocal(s1))
    const float r2 = make_div(s2).y;       // CR 1/s2
    const int tw = t * 33;
    const int tb = t * 132;

    float x[IN];
    const float2* mr = (const float2*)(m + (size_t)row * IN);
    #pragma unroll
    for (int i = 0; i < 5; ++i) {
        float2 v = mr[i];
        x[2 * i] = v.x; x[2 * i + 1] = v.y;
    }

    // ---- Layer 1: ascending asm-FMA chain from 0, bias after, h*(1/s1), rndne ----
    for (int j = 0; j < HID; ++j) {                  // uniform j -> weights via SGPR
        const float* wr = &g_W1qf[j * IN];
        float acc = f_fma_s(x[0], wr[0], 0.0f);
        #pragma unroll
        for (int k = 1; k < IN; ++k) acc = f_fma_s(x[k], wr[k], acc);
        float h = f_add(acc, b1[j]);
        float r = f_rndne(f_mul(h, r1));             // recip-multiply, single rounding
        r = fminf(15.f, fmaxf(0.f, r));              // relu folded: neg -> clamp 0
        codes8[tb + j] = (unsigned char)r;
    }

    // Rebuild a1 = code * s1 (single f32 mul, = reference's clip(...)*s)
    float a1[HID];
    #pragma unroll
    for (int w = 0; w < 32; ++w) {
        unsigned int u = codes[tw + w];
        a1[4 * w + 0] = f_mul((float)(u & 0xFFu), s1);
        a1[4 * w + 1] = f_mul((float)((u >> 8) & 0xFFu), s1);
        a1[4 * w + 2] = f_mul((float)((u >> 16) & 0xFFu), s1);
        a1[4 * w + 3] = f_mul((float)(u >> 24), s1);
    }

    // ---- Layer 2: 128-term ascending asm-FMA chain per output ----
    for (int j = 0; j < HID; ++j) {
        const float* wr = &g_W2qf[j * HID];
        float acc = f_fma_s(a1[0], wr[0], 0.0f);
        #pragma unroll
        for (int k = 1; k < HID; ++k) acc = f_fma_s(a1[k], wr[k], acc);
        float h = f_add(acc, b2[j]);
        float r = f_rndne(f_mul(h, r2));             // recip-multiply
        r = fminf(15.f, fmaxf(0.f, r));
        codes8[tb + j] = (unsigned char)r;
    }

    // Rebuild a2 = code * s2
    float a2[HID];
    #pragma unroll
    for (int w = 0; w < 32; ++w) {
        unsigned int u = codes[tw + w];
        a2[4 * w + 0] = f_mul((float)(u & 0xFFu), s2);
        a2[4 * w + 1] = f_mul((float)((u >> 8) & 0xFFu), s2);
        a2[4 * w + 2] = f_mul((float)((u >> 16) & 0xFFu), s2);
        a2[4 * w + 3] = f_mul((float)(u >> 24), s2);
    }

    // ---- Layer 3: 4 ascending asm-FMA chains ----
    float o[OUT];
    #pragma unroll
    for (int oj = 0; oj < OUT; ++oj) {
        const float* wr = &g_W3qf[oj * HID];
        float acc = f_fma_s(a2[0], wr[0], 0.0f);
        #pragma unroll
        for (int k = 1; k < HID; ++k) acc = f_fma_s(a2[k], wr[k], acc);
        o[oj] = f_add(acc, b3[oj]);
    }
    *(float4*)(out + (size_t)row * OUT) = make_float4(o[0], o[1], o[2], o[3]);
}

extern "C" void kernel_launch(void* const* d_in, const int* in_sizes, int n_in,
                              void* d_out, int out_size, void* d_ws, size_t ws_size,
                              hipStream_t stream) {
    const float* m  = (const float*)d_in[0];
    const float* W1 = (const float*)d_in[1];
    const float* b1 = (const float*)d_in[2];
    const float* W2 = (const float*)d_in[3];
    const float* b2 = (const float*)d_in[4];
    const float* W3 = (const float*)d_in[5];
    const float* b3 = (const float*)d_in[6];
    const float* s1 = (const float*)d_in[7];
    const float* s2 = (const float*)d_in[8];
    const int nrows = in_sizes[0] / IN;

    prep_kernel<<<3, 256, 0, stream>>>(W1, W2, W3);
    const int nblk = (nrows + 255) / 256;
    mlp_kernel<<<nblk, 256, 0, stream>>>(m, b1, b2, b3, s1, s2, (float*)d_out, nrows);
}

// Round 12
// 3900.708 us; speedup vs baseline: 1.5205x; 1.5205x over previous
//
#include <hip/hip_runtime.h>

#define IN 10
#define HID 128
#define OUT 4

// Dequantized f32 weights (static device globals; rewritten every launch).
__device__ float g_W1qf[HID * IN];
__device__ float g_W2qf[HID * HID];
__device__ float g_W3qf[OUT * HID];

// ---------- asm-protected f32 ops (immune to fast-math/reassoc/contract) ----------
__device__ __forceinline__ float f_fma(float a, float b, float c) {
    float d; asm("v_fma_f32 %0, %1, %2, %3" : "=v"(d) : "v"(a), "v"(b), "v"(c)); return d;
}
__device__ __forceinline__ float f_fma_s(float a, float w, float c) {   // 1 SGPR legal in VOP3
    float d; asm("v_fma_f32 %0, %1, %2, %3" : "=v"(d) : "v"(a), "s"(w), "v"(c)); return d;
}
__device__ __forceinline__ float f_mul(float a, float b) {
    float d; asm("v_mul_f32 %0, %1, %2" : "=v"(d) : "v"(a), "v"(b)); return d;
}
__device__ __forceinline__ float f_add(float a, float b) {
    float d; asm("v_add_f32 %0, %1, %2" : "=v"(d) : "v"(a), "v"(b)); return d;
}
__device__ __forceinline__ float f_sub(float a, float b) {
    float d; asm("v_sub_f32 %0, %1, %2" : "=v"(d) : "v"(a), "v"(b)); return d;
}
__device__ __forceinline__ float f_rndne(float a) {   // round half to even = np.round
    float d; asm("v_rndne_f32 %0, %1" : "=v"(d) : "v"(a)); return d;
}
__device__ __forceinline__ float f_rcp(float a) {
    float d; asm("v_rcp_f32 %0, %1" : "=v"(d) : "v"(a)); return d;
}

// CR reciprocal / CR divide (Markstein). d.y = correctly-rounded 1/s.
struct DivCR { float y, ns; };
__device__ __forceinline__ DivCR make_div(float s) {
    DivCR d;
    d.ns = f_sub(0.0f, s);
    float y0 = f_rcp(s);
    float e0 = f_fma(d.ns, y0, 1.0f);
    float y1 = f_fma(e0, y0, y0);
    float e1 = f_fma(d.ns, y1, 1.0f);
    d.y = f_fma(e1, y1, y1);
    return d;
}
__device__ __forceinline__ float div_cr(float h, DivCR d) {
    float q0 = f_mul(h, d.y);
    float r  = f_fma(d.ns, q0, h);
    return f_fma(r, d.y, q0);
}

// prep: f32 max-reduce -> s = max/7 (CR divide) -> r = rndne(W*(1/s)) clamp ±7
// -> Wq = r*s. Bit-identical to R11 (passed).
__global__ void prep_kernel(const float* __restrict__ W1,
                            const float* __restrict__ W2,
                            const float* __restrict__ W3) {
    __shared__ float red[256];
    __shared__ float sS;
    const int t = threadIdx.x;
    const int which = blockIdx.x;

    const float* W; float* Wo; int n;
    if (which == 0)      { W = W1; Wo = g_W1qf; n = HID * IN; }
    else if (which == 1) { W = W2; Wo = g_W2qf; n = HID * HID; }
    else                 { W = W3; Wo = g_W3qf; n = OUT * HID; }

    float mx = 0.f;
    for (int i = t; i < n; i += 256) mx = fmaxf(mx, fabsf(W[i]));
    red[t] = mx;
    __syncthreads();
    for (int s = 128; s > 0; s >>= 1) {
        if (t < s) red[t] = fmaxf(red[t], red[t + s]);
        __syncthreads();
    }
    if (t == 0) {
        DivCR d7 = make_div(7.0f);
        sS = div_cr(red[0], d7);
    }
    __syncthreads();
    const float s = sS;
    const float rs = make_div(s).y;

    for (int i = t; i < n; i += 256) {
        float r = f_rndne(f_mul(W[i], rs));
        r = fminf(7.f, fmaxf(-7.f, r));
        Wo[i] = f_mul(r, s);
    }
}

// Quant epilogue: h -> uint code (bit-identical op sequence to R11).
__device__ __forceinline__ unsigned int quant_code(float acc, float bias, float recip) {
    float h = f_add(acc, bias);
    float r = f_rndne(f_mul(h, recip));
    r = fminf(15.f, fmaxf(0.f, r));
    return (unsigned int)r;
}

__global__ __launch_bounds__(256) void mlp_kernel(
    const float* __restrict__ m,
    const float* __restrict__ b1,
    const float* __restrict__ b2,
    const float* __restrict__ b3,
    const float* __restrict__ s_act1,
    const float* __restrict__ s_act2,
    float* __restrict__ out, int nrows)
{
    // Packed quant codes: 33 words/thread (32 used + 1 pad -> bank spread).
    __shared__ unsigned int codes[256 * 33];

    const int t = threadIdx.x;
    const int row = blockIdx.x * 256 + t;
    if (row >= nrows) return;              // no barriers below -> safe early-out

    const float s1 = s_act1[0];
    const float s2 = s_act2[0];
    const float r1 = make_div(s1).y;       // CR 1/s1
    const float r2 = make_div(s2).y;       // CR 1/s2
    const int tw = t * 33;

    float x[IN];
    const float2* mr = (const float2*)(m + (size_t)row * IN);
    #pragma unroll
    for (int i = 0; i < 5; ++i) {
        float2 v = mr[i];
        x[2 * i] = v.x; x[2 * i + 1] = v.y;
    }

    // ---- Layer 1: groups of 4 j, 4 independent ascending FMA chains ----
    #pragma unroll 1
    for (int g = 0; g < 32; ++g) {
        const float* w0 = &g_W1qf[(4 * g + 0) * IN];
        const float* w1 = &g_W1qf[(4 * g + 1) * IN];
        const float* w2 = &g_W1qf[(4 * g + 2) * IN];
        const float* w3 = &g_W1qf[(4 * g + 3) * IN];
        float a0 = f_fma_s(x[0], w0[0], 0.0f);
        float a1c = f_fma_s(x[0], w1[0], 0.0f);
        float a2c = f_fma_s(x[0], w2[0], 0.0f);
        float a3c = f_fma_s(x[0], w3[0], 0.0f);
        #pragma unroll
        for (int k = 1; k < IN; ++k) {
            a0  = f_fma_s(x[k], w0[k], a0);
            a1c = f_fma_s(x[k], w1[k], a1c);
            a2c = f_fma_s(x[k], w2[k], a2c);
            a3c = f_fma_s(x[k], w3[k], a3c);
        }
        unsigned int c0 = quant_code(a0,  b1[4 * g + 0], r1);
        unsigned int c1 = quant_code(a1c, b1[4 * g + 1], r1);
        unsigned int c2 = quant_code(a2c, b1[4 * g + 2], r1);
        unsigned int c3 = quant_code(a3c, b1[4 * g + 3], r1);
        codes[tw + g] = c0 | (c1 << 8) | (c2 << 16) | (c3 << 24);
    }

    // Unpack act[k] = code * s1 once (reused by all 128 L2 chains).
    float act[HID];
    #pragma unroll
    for (int w = 0; w < 32; ++w) {
        unsigned int u = codes[tw + w];
        act[4 * w + 0] = f_mul((float)(u & 0xFFu), s1);
        act[4 * w + 1] = f_mul((float)((u >> 8) & 0xFFu), s1);
        act[4 * w + 2] = f_mul((float)((u >> 16) & 0xFFu), s1);
        act[4 * w + 3] = f_mul((float)(u >> 24), s1);
    }

    // ---- Layer 2: groups of 4 j, 4 independent 128-FMA chains ----
    #pragma unroll 1
    for (int g = 0; g < 32; ++g) {
        const float* w0 = &g_W2qf[(4 * g + 0) * HID];
        const float* w1 = &g_W2qf[(4 * g + 1) * HID];
        const float* w2 = &g_W2qf[(4 * g + 2) * HID];
        const float* w3 = &g_W2qf[(4 * g + 3) * HID];
        float a0 = f_fma_s(act[0], w0[0], 0.0f);
        float a1c = f_fma_s(act[0], w1[0], 0.0f);
        float a2c = f_fma_s(act[0], w2[0], 0.0f);
        float a3c = f_fma_s(act[0], w3[0], 0.0f);
        #pragma unroll
        for (int k = 1; k < HID; ++k) {
            a0  = f_fma_s(act[k], w0[k], a0);
            a1c = f_fma_s(act[k], w1[k], a1c);
            a2c = f_fma_s(act[k], w2[k], a2c);
            a3c = f_fma_s(act[k], w3[k], a3c);
        }
        unsigned int c0 = quant_code(a0,  b2[4 * g + 0], r2);
        unsigned int c1 = quant_code(a1c, b2[4 * g + 1], r2);
        unsigned int c2 = quant_code(a2c, b2[4 * g + 2], r2);
        unsigned int c3 = quant_code(a3c, b2[4 * g + 3], r2);
        codes[tw + g] = c0 | (c1 << 8) | (c2 << 16) | (c3 << 24);
    }

    // Unpack act[k] = code * s2 (reuse register array).
    #pragma unroll
    for (int w = 0; w < 32; ++w) {
        unsigned int u = codes[tw + w];
        act[4 * w + 0] = f_mul((float)(u & 0xFFu), s2);
        act[4 * w + 1] = f_mul((float)((u >> 8) & 0xFFu), s2);
        act[4 * w + 2] = f_mul((float)((u >> 16) & 0xFFu), s2);
        act[4 * w + 3] = f_mul((float)(u >> 24), s2);
    }

    // ---- Layer 3: 4 independent ascending chains ----
    const float* u0 = &g_W3qf[0 * HID];
    const float* u1 = &g_W3qf[1 * HID];
    const float* u2 = &g_W3qf[2 * HID];
    const float* u3 = &g_W3qf[3 * HID];
    float o0 = f_fma_s(act[0], u0[0], 0.0f);
    float o1 = f_fma_s(act[0], u1[0], 0.0f);
    float o2 = f_fma_s(act[0], u2[0], 0.0f);
    float o3 = f_fma_s(act[0], u3[0], 0.0f);
    #pragma unroll
    for (int k = 1; k < HID; ++k) {
        o0 = f_fma_s(act[k], u0[k], o0);
        o1 = f_fma_s(act[k], u1[k], o1);
        o2 = f_fma_s(act[k], u2[k], o2);
        o3 = f_fma_s(act[k], u3[k], o3);
    }
    float4 o;
    o.x = f_add(o0, b3[0]);
    o.y = f_add(o1, b3[1]);
    o.z = f_add(o2, b3[2]);
    o.w = f_add(o3, b3[3]);
    *(float4*)(out + (size_t)row * OUT) = o;
}

extern "C" void kernel_launch(void* const* d_in, const int* in_sizes, int n_in,
                              void* d_out, int out_size, void* d_ws, size_t ws_size,
                              hipStream_t stream) {
    const float* m  = (const float*)d_in[0];
    const float* W1 = (const float*)d_in[1];
    const float* b1 = (const float*)d_in[2];
    const float* W2 = (const float*)d_in[3];
    const float* b2 = (const float*)d_in[4];
    const float* W3 = (const float*)d_in[5];
    const float* b3 = (const float*)d_in[6];
    const float* s1 = (const float*)d_in[7];
    const float* s2 = (const float*)d_in[8];
    const int nrows = in_sizes[0] / IN;

    prep_kernel<<<3, 256, 0, stream>>>(W1, W2, W3);
    const int nblk = (nrows + 255) / 256;
    mlp_kernel<<<nblk, 256, 0, stream>>>(m, b1, b2, b3, s1, s2, (float*)d_out, nrows);
}

// Round 13
// 1874.237 us; speedup vs baseline: 3.1644x; 2.0812x over previous
//
#include <hip/hip_runtime.h>

#define IN 10
#define HID 128
#define OUT 4

// Dequantized f32 weights (static device globals; rewritten every launch).
__device__ float g_W1qf[HID * IN];
__device__ float g_W2qf[HID * HID];
__device__ float g_W3qf[OUT * HID];

// ---------- asm-protected f32 ops (immune to fast-math/reassoc/contract) ----------
__device__ __forceinline__ float f_fma(float a, float b, float c) {
    float d; asm("v_fma_f32 %0, %1, %2, %3" : "=v"(d) : "v"(a), "v"(b), "v"(c)); return d;
}
__device__ __forceinline__ float f_fma_s(float a, float w, float c) {   // 1 SGPR legal in VOP3
    float d; asm("v_fma_f32 %0, %1, %2, %3" : "=v"(d) : "v"(a), "s"(w), "v"(c)); return d;
}
__device__ __forceinline__ float f_mul(float a, float b) {
    float d; asm("v_mul_f32 %0, %1, %2" : "=v"(d) : "v"(a), "v"(b)); return d;
}
__device__ __forceinline__ float f_add(float a, float b) {
    float d; asm("v_add_f32 %0, %1, %2" : "=v"(d) : "v"(a), "v"(b)); return d;
}
__device__ __forceinline__ float f_sub(float a, float b) {
    float d; asm("v_sub_f32 %0, %1, %2" : "=v"(d) : "v"(a), "v"(b)); return d;
}
__device__ __forceinline__ float f_rndne(float a) {   // round half to even = np.round
    float d; asm("v_rndne_f32 %0, %1" : "=v"(d) : "v"(a)); return d;
}
__device__ __forceinline__ float f_rcp(float a) {
    float d; asm("v_rcp_f32 %0, %1" : "=v"(d) : "v"(a)); return d;
}

// CR reciprocal / CR divide (Markstein). d.y = correctly-rounded 1/s.
struct DivCR { float y, ns; };
__device__ __forceinline__ DivCR make_div(float s) {
    DivCR d;
    d.ns = f_sub(0.0f, s);
    float y0 = f_rcp(s);
    float e0 = f_fma(d.ns, y0, 1.0f);
    float y1 = f_fma(e0, y0, y0);
    float e1 = f_fma(d.ns, y1, 1.0f);
    d.y = f_fma(e1, y1, y1);
    return d;
}
__device__ __forceinline__ float div_cr(float h, DivCR d) {
    float q0 = f_mul(h, d.y);
    float r  = f_fma(d.ns, q0, h);
    return f_fma(r, d.y, q0);
}

// prep: f32 max-reduce -> s = max/7 (CR divide) -> r = rndne(W*(1/s)) clamp ±7
// -> Wq = r*s. Bit-identical to R11/R12 (passed).
__global__ void prep_kernel(const float* __restrict__ W1,
                            const float* __restrict__ W2,
                            const float* __restrict__ W3) {
    __shared__ float red[256];
    __shared__ float sS;
    const int t = threadIdx.x;
    const int which = blockIdx.x;

    const float* W; float* Wo; int n;
    if (which == 0)      { W = W1; Wo = g_W1qf; n = HID * IN; }
    else if (which == 1) { W = W2; Wo = g_W2qf; n = HID * HID; }
    else                 { W = W3; Wo = g_W3qf; n = OUT * HID; }

    float mx = 0.f;
    for (int i = t; i < n; i += 256) mx = fmaxf(mx, fabsf(W[i]));
    red[t] = mx;
    __syncthreads();
    for (int s = 128; s > 0; s >>= 1) {
        if (t < s) red[t] = fmaxf(red[t], red[t + s]);
        __syncthreads();
    }
    if (t == 0) {
        DivCR d7 = make_div(7.0f);
        sS = div_cr(red[0], d7);
    }
    __syncthreads();
    const float s = sS;
    const float rs = make_div(s).y;

    for (int i = t; i < n; i += 256) {
        float r = f_rndne(f_mul(W[i], rs));
        r = fminf(7.f, fmaxf(-7.f, r));
        Wo[i] = f_mul(r, s);
    }
}

// Quant epilogue: h -> uint code (bit-identical op sequence to R11/R12).
__device__ __forceinline__ unsigned int quant_code(float acc, float bias, float recip) {
    float h = f_add(acc, bias);
    float r = f_rndne(f_mul(h, recip));
    r = fminf(15.f, fmaxf(0.f, r));
    return (unsigned int)r;
}

__global__ __launch_bounds__(256, 2) void mlp_kernel(
    const float* __restrict__ m,
    const float* __restrict__ b1,
    const float* __restrict__ b2,
    const float* __restrict__ b3,
    const float* __restrict__ s_act1,
    const float* __restrict__ s_act2,
    float* __restrict__ out, int nrows)
{
    // W2 staged in LDS: 128x128 f32 = 64 KB (the static per-workgroup max).
    __shared__ float sW2[HID * HID];

    const int t = threadIdx.x;

    // Cooperative stage (coalesced float4), BEFORE any early-out.
    {
        const float4* src = (const float4*)g_W2qf;
        float4* dst = (float4*)sW2;
        #pragma unroll
        for (int i = 0; i < 16; ++i) dst[t + 256 * i] = src[t + 256 * i];
    }
    __syncthreads();

    const int row = blockIdx.x * 256 + t;
    if (row >= nrows) return;               // no barriers below

    const float s1 = s_act1[0];
    const float s2 = s_act2[0];
    const float r1 = make_div(s1).y;        // CR 1/s1
    const float r2 = make_div(s2).y;        // CR 1/s2

    float x[IN];
    const float2* mr = (const float2*)(m + (size_t)row * IN);
    #pragma unroll
    for (int i = 0; i < 5; ++i) {
        float2 v = mr[i];
        x[2 * i] = v.x; x[2 * i + 1] = v.y;
    }

    // ---- Layer 1: fully unrolled (static act[] indices -> VGPR residency) ----
    float act[HID];
    #pragma unroll
    for (int g = 0; g < 32; ++g) {
        const float* w0 = &g_W1qf[(4 * g + 0) * IN];
        const float* w1 = &g_W1qf[(4 * g + 1) * IN];
        const float* w2 = &g_W1qf[(4 * g + 2) * IN];
        const float* w3 = &g_W1qf[(4 * g + 3) * IN];
        float a0 = f_fma_s(x[0], w0[0], 0.0f);
        float a1c = f_fma_s(x[0], w1[0], 0.0f);
        float a2c = f_fma_s(x[0], w2[0], 0.0f);
        float a3c = f_fma_s(x[0], w3[0], 0.0f);
        #pragma unroll
        for (int k = 1; k < IN; ++k) {
            a0  = f_fma_s(x[k], w0[k], a0);
            a1c = f_fma_s(x[k], w1[k], a1c);
            a2c = f_fma_s(x[k], w2[k], a2c);
            a3c = f_fma_s(x[k], w3[k], a3c);
        }
        unsigned int c0 = quant_code(a0,  b1[4 * g + 0], r1);
        unsigned int c1 = quant_code(a1c, b1[4 * g + 1], r1);
        unsigned int c2 = quant_code(a2c, b1[4 * g + 2], r1);
        unsigned int c3 = quant_code(a3c, b1[4 * g + 3], r1);
        act[4 * g + 0] = f_mul((float)c0, s1);
        act[4 * g + 1] = f_mul((float)c1, s1);
        act[4 * g + 2] = f_mul((float)c2, s1);
        act[4 * g + 3] = f_mul((float)c3, s1);
    }

    // ---- Layer 2 (LDS weights, 4-way j-ILP) with Layer 3 FUSED ----
    // L3 chains (ascending k == ascending j order) accumulate as act2 is born.
    float o0 = 0.0f, o1 = 0.0f, o2 = 0.0f, o3 = 0.0f;

    #pragma unroll 1
    for (int g = 0; g < 32; ++g) {
        const float4* w0 = (const float4*)&sW2[(4 * g + 0) * HID];
        const float4* w1 = (const float4*)&sW2[(4 * g + 1) * HID];
        const float4* w2 = (const float4*)&sW2[(4 * g + 2) * HID];
        const float4* w3 = (const float4*)&sW2[(4 * g + 3) * HID];
        float a0 = 0.0f, a1c = 0.0f, a2c = 0.0f, a3c = 0.0f;
        #pragma unroll
        for (int kk = 0; kk < 32; ++kk) {
            float4 q0 = w0[kk];
            float4 q1 = w1[kk];
            float4 q2 = w2[kk];
            float4 q3 = w3[kk];
            a0  = f_fma(act[4 * kk + 0], q0.x, a0);
            a1c = f_fma(act[4 * kk + 0], q1.x, a1c);
            a2c = f_fma(act[4 * kk + 0], q2.x, a2c);
            a3c = f_fma(act[4 * kk + 0], q3.x, a3c);
            a0  = f_fma(act[4 * kk + 1], q0.y, a0);
            a1c = f_fma(act[4 * kk + 1], q1.y, a1c);
            a2c = f_fma(act[4 * kk + 1], q2.y, a2c);
            a3c = f_fma(act[4 * kk + 1], q3.y, a3c);
            a0  = f_fma(act[4 * kk + 2], q0.z, a0);
            a1c = f_fma(act[4 * kk + 2], q1.z, a1c);
            a2c = f_fma(act[4 * kk + 2], q2.z, a2c);
            a3c = f_fma(act[4 * kk + 2], q3.z, a3c);
            a0  = f_fma(act[4 * kk + 3], q0.w, a0);
            a1c = f_fma(act[4 * kk + 3], q1.w, a1c);
            a2c = f_fma(act[4 * kk + 3], q2.w, a2c);
            a3c = f_fma(act[4 * kk + 3], q3.w, a3c);
        }
        unsigned int c0 = quant_code(a0,  b2[4 * g + 0], r2);
        unsigned int c1 = quant_code(a1c, b2[4 * g + 1], r2);
        unsigned int c2 = quant_code(a2c, b2[4 * g + 2], r2);
        unsigned int c3 = quant_code(a3c, b2[4 * g + 3], r2);
        float v0 = f_mul((float)c0, s2);
        float v1 = f_mul((float)c1, s2);
        float v2 = f_mul((float)c2, s2);
        float v3 = f_mul((float)c3, s2);
        // Fused L3: ascending k = 4g..4g+3 appended to each output chain.
        o0 = f_fma_s(v0, g_W3qf[0 * HID + 4 * g + 0], o0);
        o1 = f_fma_s(v0, g_W3qf[1 * HID + 4 * g + 0], o1);
        o2 = f_fma_s(v0, g_W3qf[2 * HID + 4 * g + 0], o2);
        o3 = f_fma_s(v0, g_W3qf[3 * HID + 4 * g + 0], o3);
        o0 = f_fma_s(v1, g_W3qf[0 * HID + 4 * g + 1], o0);
        o1 = f_fma_s(v1, g_W3qf[1 * HID + 4 * g + 1], o1);
        o2 = f_fma_s(v1, g_W3qf[2 * HID + 4 * g + 1], o2);
        o3 = f_fma_s(v1, g_W3qf[3 * HID + 4 * g + 1], o3);
        o0 = f_fma_s(v2, g_W3qf[0 * HID + 4 * g + 2], o0);
        o1 = f_fma_s(v2, g_W3qf[1 * HID + 4 * g + 2], o1);
        o2 = f_fma_s(v2, g_W3qf[2 * HID + 4 * g + 2], o2);
        o3 = f_fma_s(v2, g_W3qf[3 * HID + 4 * g + 2], o3);
        o0 = f_fma_s(v3, g_W3qf[0 * HID + 4 * g + 3], o0);
        o1 = f_fma_s(v3, g_W3qf[1 * HID + 4 * g + 3], o1);
        o2 = f_fma_s(v3, g_W3qf[2 * HID + 4 * g + 3], o2);
        o3 = f_fma_s(v3, g_W3qf[3 * HID + 4 * g + 3], o3);
    }

    float4 o;
    o.x = f_add(o0, b3[0]);
    o.y = f_add(o1, b3[1]);
    o.z = f_add(o2, b3[2]);
    o.w = f_add(o3, b3[3]);
    *(float4*)(out + (size_t)row * OUT) = o;
}

extern "C" void kernel_launch(void* const* d_in, const int* in_sizes, int n_in,
                              void* d_out, int out_size, void* d_ws, size_t ws_size,
                              hipStream_t stream) {
    const float* m  = (const float*)d_in[0];
    const float* W1 = (const float*)d_in[1];
    const float* b1 = (const float*)d_in[2];
    const float* W2 = (const float*)d_in[3];
    const float* b2 = (const float*)d_in[4];
    const float* W3 = (const float*)d_in[5];
    const float* b3 = (const float*)d_in[6];
    const float* s1 = (const float*)d_in[7];
    const float* s2 = (const float*)d_in[8];
    const int nrows = in_sizes[0] / IN;

    prep_kernel<<<3, 256, 0, stream>>>(W1, W2, W3);
    const int nblk = (nrows + 255) / 256;
    mlp_kernel<<<nblk, 256, 0, stream>>>(m, b1, b2, b3, s1, s2, (float*)d_out, nrows);
}